// Round 2
// baseline (456.990 us; speedup 1.0000x reference)
//
#include <hip/hip_runtime.h>
#include <math.h>

#define NFFT   2048
#define N1     1024
#define K1     1025
#define KPAD   36
#define MTOT   1097   // K1 + 2*KPAD
#define NFRAMES 1001
#define TLEN   120000
#define BATCH  8
#define FPER   120
#define PIF 3.14159265358979323846f

// ============================================================================
// One WAVE (64 threads) per frame. 16 cpx per thread = full 1024-pt FFT in
// one wave: stages A,B (spans 512/256 and 128/64) and C,D (32/16 and 8/4) and
// E (2/1) are register-local; only two LDS transposes + one k-order store per
// FFT. ZERO __syncthreads: all LDS dependencies are same-wave (per-wave DS
// ops execute in order; validated by r1's barrier removal passing on HW).
//
// LDS element swizzle SW(m) = m ^ ((m>>6)&15): bank-pair = (m&15)^((m>>6)&15).
// Enumerated conflict-minimal (4 lanes/pair = b64 bandwidth floor) for all
// patterns: RT1-write (m=t+64r), RT1-read/RT2-write (m=64(t>>2)+4u+(t&3)),
// RT2-read (m=4t+256c+e), k-order store (k=rev2(e)<<8|rev6(t)<<2|rev2(c)),
// unpack reads (kk=t+64c and (1024-kk)&1023).
// ============================================================================

typedef float2 cpx;
__device__ __forceinline__ cpx cadd(cpx a, cpx b){ return make_float2(a.x+b.x, a.y+b.y); }
__device__ __forceinline__ cpx csub(cpx a, cpx b){ return make_float2(a.x-b.x, a.y-b.y); }
__device__ __forceinline__ cpx cmul(cpx a, cpx b){ return make_float2(a.x*b.x - a.y*b.y, a.x*b.y + a.y*b.x); }

__device__ __forceinline__ int SW(int m){ return m ^ ((m >> 6) & 15); }

// radix-4 DIF butterfly, exact arithmetic of r1's dif_fused (two fused radix-2
// DIF stages; quarter-order q0,q2,q1,q3 -> global bit-reversed output).
__device__ __forceinline__ void bf4(cpx& x0, cpx& x1, cpx& x2, cpx& x3, cpx w1)
{
    cpx w1n = make_float2(w1.y, -w1.x);                       // -i*w1
    cpx w2  = make_float2(w1.x*w1.x - w1.y*w1.y, 2.0f*w1.x*w1.y);
    cpx a1 = cadd(x0, x2);
    cpx c1 = cmul(csub(x0, x2), w1);
    cpx b1 = cadd(x1, x3);
    cpx d1 = cmul(csub(x1, x3), w1n);
    x0 = cadd(a1, b1);
    x1 = cmul(csub(a1, b1), w2);
    x2 = cadd(c1, d1);
    x3 = cmul(csub(c1, d1), w2);
}
// last stage (spans 2/1): twiddles 1 and -i, no multiplies (== r1 dif_last2)
__device__ __forceinline__ void bf4_last(cpx& x0, cpx& x1, cpx& x2, cpx& x3)
{
    cpx a1 = cadd(x0, x2);
    cpx c1 = csub(x0, x2);
    cpx b1 = cadd(x1, x3);
    cpx bd = csub(x1, x3);
    cpx d1 = make_float2(bd.y, -bd.x);
    x0 = cadd(a1, b1);
    x1 = csub(a1, b1);
    x2 = cadd(c1, d1);
    x3 = csub(c1, d1);
}

// s_c now holds Z[k] in NATURAL k order (the FFT's final store un-bit-reverses)
__device__ __forceinline__ void unpack_k(const cpx* s_c, int kk, cpx w,
                                         cpx& Xk, cpx& Xm)
{
    int mm = (N1 - kk) & (N1 - 1);
    cpx Zk = s_c[SW(kk)];
    cpx Zm = s_c[SW(mm)];
    float Ex = 0.5f*(Zk.x + Zm.x), Ey = 0.5f*(Zk.y - Zm.y);
    float Ox = 0.5f*(Zk.y + Zm.y), Oy = 0.5f*(Zm.x - Zk.x);
    float tx = w.x*Ox - w.y*Oy, ty = w.x*Oy + w.y*Ox;
    Xk = make_float2(Ex + tx, Ey + ty);
    Xm = make_float2(Ex - tx, Ey - ty);
}

// (64,4): cap VGPR at 128 (13 blocks/CU are LDS-capped anyway).
// Spill canary: WRITE_SIZE must stay ~32.3 MB.
__global__ __launch_bounds__(64, 4)
void cheaptrick_kernel(const float* __restrict__ x,
                       const float* __restrict__ f0in,
                       float* __restrict__ out)
{
    __shared__ cpx   s_c[1024];
    __shared__ float s_P[1026];
    // s_C aliases s_c (lifetime-disjoint; cross-type boundaries are fenced)
    float* s_C = (float*)s_c;

    const int t  = threadIdx.x;          // 0..63 == lane (single wave)
    const int vv = t & 3;
    const int n  = blockIdx.x;
    const int b  = blockIdx.y;

    float f0 = f0in[b * NFRAMES + n];
    const float F_MIN = 72000.0f / 2045.0f;
    if (f0 <= F_MIN) f0 = 500.0f;

    cpx z[16];

    // ---- pack1: frame extraction + window; z[r] = (v(2m), v(2m+1)), m=t+64r
    {
        const float* xrow = x + (size_t)b * TLEN;
        const int base_idx = n * FPER - N1;
        float hwl = rintf(36000.0f / f0);
        float sw2 = 0.0f, swn = 0.0f, sfw = 0.0f;
        cpx wn[16];
#pragma unroll
        for (int r = 0; r < 16; ++r) {
            int m  = t + 64 * r;
            int i0 = base_idx + 2 * m;
            float v0, v1;
            if (i0 >= 0 && i0 + 1 <= TLEN - 1) {       // aligned pair (i0 even)
                float2 fv = *reinterpret_cast<const float2*>(xrow + i0);
                v0 = fv.x; v1 = fv.y;
            } else {
                v0 = xrow[max(0, min(TLEN - 1, i0))];
                v1 = xrow[max(0, min(TLEN - 1, i0 + 1))];
            }
            float rel0 = (float)(2 * m - N1);
            float rel1 = rel0 + 1.0f;
            float w0 = 0.0f, w1 = 0.0f;
            if (fabsf(rel0) <= hwl) w0 = 0.5f * __cosf(PIF * rel0 / 36000.0f * f0) + 0.5f;
            if (fabsf(rel1) <= hwl) w1 = 0.5f * __cosf(PIF * rel1 / 36000.0f * f0) + 0.5f;
            sw2 += w0 * w0 + w1 * w1;
            swn += w0 + w1;
            sfw += v0 * w0 + v1 * w1;
            z[r]  = make_float2(v0 * w0, v1 * w1);
            wn[r] = make_float2(w0, w1);
        }
#pragma unroll
        for (int off = 32; off > 0; off >>= 1) {
            sw2 += __shfl_down(sw2, off, 64);
            swn += __shfl_down(swn, off, 64);
            sfw += __shfl_down(sfw, off, 64);
        }
        sw2 = __shfl(sw2, 0, 64);
        swn = __shfl(swn, 0, 64);
        sfw = __shfl(sfw, 0, 64);
        float wscale = 1.0f / sqrtf(sw2);
        float dc = sfw / swn;
#pragma unroll
        for (int r = 0; r < 16; ++r) {
            z[r].x = wscale * (z[r].x - dc * wn[r].x);
            z[r].y = wscale * (z[r].y - dc * wn[r].y);
        }
    }

    // ---- twiddles, computed once, reused by all 3 FFTs ----
    cpx wA[4], wC[4], wB, wD, wU[8];
    {
        float sn, cs;
#pragma unroll
        for (int j = 0; j < 4; ++j) {
            __sincosf(-PIF * (float)(t + 64 * j) * (1.0f / 512.0f), &sn, &cs);
            wA[j] = make_float2(cs, sn);               // W_1024^(t+64j)
        }
        __sincosf(-PIF * (float)t * (1.0f / 128.0f), &sn, &cs);
        wB = make_float2(cs, sn);                      // W_256^t
#pragma unroll
        for (int a = 0; a < 4; ++a) {
            __sincosf(-PIF * (float)(4 * a + vv) * (1.0f / 32.0f), &sn, &cs);
            wC[a] = make_float2(cs, sn);               // W_64^(4a+v)
        }
        __sincosf(-PIF * (float)vv * (1.0f / 8.0f), &sn, &cs);
        wD = make_float2(cs, sn);                      // W_16^v
#pragma unroll
        for (int c = 0; c < 8; ++c) {
            __sincosf(-PIF * (float)(t + 64 * c) * (1.0f / 1024.0f), &sn, &cs);
            wU[c] = make_float2(cs, sn);               // W_2048^(t+64c)
        }
    }
    const cpx wmid = make_float2(0.0f, -1.0f);         // W_2048^512
    const int r6 = (int)(__brev((unsigned)t) >> 26);   // rev6(t)

#pragma unroll 1
    for (int pass = 0; pass < 3; ++pass) {
        if (pass != 0) {
            // pack even extension of s_P (FFT2: logP ; FFT3: lifted cepstrum)
#pragma unroll
            for (int r = 0; r < 8; ++r) {              // m <= 511: direct pair
                int m = t + 64 * r;
                z[r] = make_float2(s_P[2 * m], s_P[2 * m + 1]);
            }
#pragma unroll
            for (int r = 8; r < 16; ++r) {             // m >= 512: mirrored
                int m = t + 64 * r;
                float v0, v1;
                if (m == 512) { v0 = s_P[1024]; v1 = s_P[1023]; }
                else          { v0 = s_P[2048 - 2 * m]; v1 = s_P[2047 - 2 * m]; }
                z[r] = make_float2(v0, v1);
            }
        }

        // ================= 1024-pt FFT, fully wave-local =================
        // stage A (M=1024): butterflies i0 = t+64j, slots {j, j+4, j+8, j+12}
#pragma unroll
        for (int j = 0; j < 4; ++j) bf4(z[j], z[j+4], z[j+8], z[j+12], wA[j]);
        // stage B (M=256): per 256-block, slots {4q..4q+3}, twiddle W_256^t
#pragma unroll
        for (int q = 0; q < 4; ++q) bf4(z[4*q], z[4*q+1], z[4*q+2], z[4*q+3], wB);
        // RT1: write m = t+64r ; read m = 64*(t>>2) + 4u + (t&3)
#pragma unroll
        for (int r = 0; r < 16; ++r) s_c[(t + 64 * r) ^ r] = z[r];
#pragma unroll
        for (int u = 0; u < 16; ++u) {
            int m = 64 * (t >> 2) + 4 * u + vv;
            z[u] = s_c[m ^ (t >> 2)];
        }
        // stage C (M=64): butterflies r=4a+v, slots {a, a+4, a+8, a+12}
#pragma unroll
        for (int a = 0; a < 4; ++a) bf4(z[a], z[a+4], z[a+8], z[a+12], wC[a]);
        // stage D (M=16): slots {4h..4h+3}, twiddle W_16^v
#pragma unroll
        for (int h = 0; h < 4; ++h) bf4(z[4*h], z[4*h+1], z[4*h+2], z[4*h+3], wD);
        // RT2: write back same layout ; read quads m = 4t + 256c + e
#pragma unroll
        for (int u = 0; u < 16; ++u) {
            int m = 64 * (t >> 2) + 4 * u + vv;
            s_c[m ^ (t >> 2)] = z[u];
        }
#pragma unroll
        for (int c = 0; c < 4; ++c)
#pragma unroll
            for (int e = 0; e < 4; ++e) {
                int m = 4 * t + 256 * c + e;
                z[4 * c + e] = s_c[SW(m)];
            }
        // stage E (M=4), then store un-bit-reversed: k = brev10(m)
#pragma unroll
        for (int c = 0; c < 4; ++c) bf4_last(z[4*c], z[4*c+1], z[4*c+2], z[4*c+3]);
#pragma unroll
        for (int c = 0; c < 4; ++c) {
            int rc = ((c & 1) << 1) | (c >> 1);
#pragma unroll
            for (int e = 0; e < 4; ++e) {
                int re = ((e & 1) << 1) | (e >> 1);
                int k = (re << 8) | (r6 << 2) | rc;
                s_c[SW(k)] = z[4 * c + e];
            }
        }
        // =================================================================

        if (pass == 0) {
            // ---- unpack + power spectrum ----
#pragma unroll
            for (int c = 0; c < 8; ++c) {
                int kk = t + 64 * c;
                cpx Xk, Xm;
                unpack_k(s_c, kk, wU[c], Xk, Xm);
                s_P[kk]        = Xk.x * Xk.x + Xk.y * Xk.y;
                s_P[1024 - kk] = Xm.x * Xm.x + Xm.y * Xm.y;
            }
            if (t == 0) {
                cpx Xk, Xm;
                unpack_k(s_c, 512, wmid, Xk, Xm);
                s_P[512] = Xk.x * Xk.x + Xk.y * Xk.y;
            }

            // ---- sub-f0 replacement (kmax <= 51 < 64; read instrs precede
            //      the write instr in wave program order) ----
            float rate = f0 * (2048.0f / 24000.0f);
            int kmax = (int)floorf(rate);
            if (t <= kmax) {
                float m = rate - (float)t;
                int lo = (int)floorf(m);
                lo = max(0, min(K1 - 2, lo));
                float frac = m - (float)lo;
                float repl = s_P[lo] * (1.0f - frac) + s_P[lo + 1] * frac;
                s_P[t] += repl;
            }

            // fence: s_C(float) stores below must not reorder vs s_c(cpx)
            // loads above (TBAA cross-type alias)
            asm volatile("" ::: "memory");

            // ---- reflected cumsum: serial-19 + wave scan -> s_C ----
            float loc[19];
            float run = 0.0f;
            const int basej = t * 19;
#pragma unroll
            for (int c = 0; c < 19; ++c) {
                int j = basej + c;
                float v = 0.0f;
                if (j < MTOT) {
                    int a = abs(j - KPAD);
                    if (a > N1) a = NFFT - a;
                    v = s_P[a] * (24000.0f / 2048.0f);
                }
                run += v;
                loc[c] = run;
            }
            float sv = run;
#pragma unroll
            for (int off = 1; off < 64; off <<= 1) {
                float o = __shfl_up(sv, off, 64);
                if (t >= off) sv += o;
            }
            float prefix = sv - run;
#pragma unroll
            for (int c = 0; c < 19; ++c) {
                int j = basej + c;
                if (j < MTOT) s_C[j] = prefix + loc[c];
            }

            // ---- rectangular smoothing + log -> s_P ----
            float width = f0 * (2.0f / 3.0f);
            float wbins = width * (2048.0f / 24000.0f);
#pragma unroll
            for (int c = 0; c < 17; ++c) {
                int k = t + 64 * c;
                if (k < K1) {                          // c==16 only t==0
                    float pos_lo = (float)k - 0.5f * wbins + ((float)KPAD - 0.5f);
                    float pos_hi = pos_lo + wbins;
                    int llo = (int)floorf(pos_lo); llo = max(0, min(MTOT - 2, llo));
                    float flo = pos_lo - (float)llo;
                    float clo = s_C[llo] + (s_C[llo + 1] - s_C[llo]) * flo;
                    int lhi = (int)floorf(pos_hi); lhi = max(0, min(MTOT - 2, lhi));
                    float fhi = pos_hi - (float)lhi;
                    float chi = s_C[lhi] + (s_C[lhi + 1] - s_C[lhi]) * fhi;
                    s_P[k] = __logf((chi - clo) / width);
                }
            }

            // fence: next pass's s_c(cpx) stores must not reorder vs the
            // s_C(float) loads above
            asm volatile("" ::: "memory");
        } else if (pass == 1) {
            // ---- unpack + lifter -> s_P ----
#pragma unroll
            for (int c = 0; c < 8; ++c) {
                int kk = t + 64 * c;
                cpx Xk, Xm;
                unpack_k(s_c, kk, wU[c], Xk, Xm);
                {
                    float cep = Xk.x * (1.0f / 2048.0f);
                    float pz = PIF * f0 * ((float)kk * (1.0f / 24000.0f));
                    float s = __sinf(pz);
                    float sl = (kk != 0) ? (s / pz) : 1.0f;
                    s_P[kk] = cep * sl * (1.0f + 0.6f * s * s);
                }
                {
                    int km = 1024 - kk;                // in [513,1024], never 0
                    float cep = Xm.x * (1.0f / 2048.0f);
                    float pz = PIF * f0 * ((float)km * (1.0f / 24000.0f));
                    float s = __sinf(pz);
                    s_P[km] = cep * (s / pz) * (1.0f + 0.6f * s * s);
                }
            }
            if (t == 0) {
                cpx Xk, Xm;
                unpack_k(s_c, 512, wmid, Xk, Xm);
                float cep = Xk.x * (1.0f / 2048.0f);
                float pz = PIF * f0 * (512.0f / 24000.0f);
                float s = __sinf(pz);
                s_P[512] = cep * (s / pz) * (1.0f + 0.6f * s * s);
            }
        } else {
            // ---- unpack + store ----
            float* orow = out + (size_t)(b * NFRAMES + n) * K1;
#pragma unroll
            for (int c = 0; c < 8; ++c) {
                int kk = t + 64 * c;
                cpx Xk, Xm;
                unpack_k(s_c, kk, wU[c], Xk, Xm);
                orow[kk]        = Xk.x;
                orow[1024 - kk] = Xm.x;
            }
            if (t == 0) {
                cpx Xk, Xm;
                unpack_k(s_c, 512, wmid, Xk, Xm);
                orow[512] = Xk.x;
            }
        }
    }
}

extern "C" void kernel_launch(void* const* d_in, const int* in_sizes, int n_in,
                              void* d_out, int out_size, void* d_ws, size_t ws_size,
                              hipStream_t stream) {
    (void)in_sizes; (void)n_in; (void)d_ws; (void)ws_size; (void)out_size;
    const float* x  = (const float*)d_in[0];
    const float* f0 = (const float*)d_in[1];
    float* out = (float*)d_out;
    dim3 grid(NFRAMES, BATCH);
    hipLaunchKernelGGL(cheaptrick_kernel, grid, dim3(64), 0, stream, x, f0, out);
}

// Round 3
// 237.926 us; speedup vs baseline: 1.9207x; 1.9207x over previous
//
#include <hip/hip_runtime.h>
#include <math.h>

#define NFFT   2048
#define N1     1024
#define K1     1025
#define KPAD   36
#define MTOT   1097   // K1 + 2*KPAD
#define NFRAMES 1001
#define TLEN   120000
#define BATCH  8
#define FPER   120
#define PIF 3.14159265358979323846f

// ============================================================================
// One WAVE (64 threads) per frame. 16 cpx per thread = full 1024-pt FFT in
// one wave; ZERO __syncthreads (all LDS deps same-wave, in-order DS pipe).
// Math identical to r2 (passed on HW, absmax 0.03125). r2's failure was
// VGPR spills (launch_bounds(64,4) -> 64-VGPR cap -> 578MB scratch FETCH).
// r3 fixes ONLY the register economy:
//   - __launch_bounds__(64,2): 256-VGPR budget (occupancy is LDS-capped at
//     12 blocks/CU regardless).
//   - wn[16] (32 VGPRs, biggest transient) parked in LDS s_c during pack1
//     (s_c is dead there); read back with r2's exact arithmetic.
// Spill canary: WRITE_SIZE must return to ~32.3 MB, FETCH to ~15 MB.
//
// LDS element swizzle SW(m) = m ^ ((m>>6)&15): enumerated conflict-minimal
// (4 lanes/bank-pair = b64 floor) for all access patterns (see r2 notes).
// ============================================================================

typedef float2 cpx;
__device__ __forceinline__ cpx cadd(cpx a, cpx b){ return make_float2(a.x+b.x, a.y+b.y); }
__device__ __forceinline__ cpx csub(cpx a, cpx b){ return make_float2(a.x-b.x, a.y-b.y); }
__device__ __forceinline__ cpx cmul(cpx a, cpx b){ return make_float2(a.x*b.x - a.y*b.y, a.x*b.y + a.y*b.x); }

__device__ __forceinline__ int SW(int m){ return m ^ ((m >> 6) & 15); }

// radix-4 DIF butterfly (two fused radix-2 DIF stages; quarter-order
// q0,q2,q1,q3 -> global bit-reversed output). Arithmetic identical to r1/r2.
__device__ __forceinline__ void bf4(cpx& x0, cpx& x1, cpx& x2, cpx& x3, cpx w1)
{
    cpx w1n = make_float2(w1.y, -w1.x);                       // -i*w1
    cpx w2  = make_float2(w1.x*w1.x - w1.y*w1.y, 2.0f*w1.x*w1.y);
    cpx a1 = cadd(x0, x2);
    cpx c1 = cmul(csub(x0, x2), w1);
    cpx b1 = cadd(x1, x3);
    cpx d1 = cmul(csub(x1, x3), w1n);
    x0 = cadd(a1, b1);
    x1 = cmul(csub(a1, b1), w2);
    x2 = cadd(c1, d1);
    x3 = cmul(csub(c1, d1), w2);
}
// last stage (spans 2/1): twiddles 1 and -i, no multiplies
__device__ __forceinline__ void bf4_last(cpx& x0, cpx& x1, cpx& x2, cpx& x3)
{
    cpx a1 = cadd(x0, x2);
    cpx c1 = csub(x0, x2);
    cpx b1 = cadd(x1, x3);
    cpx bd = csub(x1, x3);
    cpx d1 = make_float2(bd.y, -bd.x);
    x0 = cadd(a1, b1);
    x1 = csub(a1, b1);
    x2 = cadd(c1, d1);
    x3 = csub(c1, d1);
}

// s_c holds Z[k] in NATURAL k order (the FFT's final store un-bit-reverses)
__device__ __forceinline__ void unpack_k(const cpx* s_c, int kk, cpx w,
                                         cpx& Xk, cpx& Xm)
{
    int mm = (N1 - kk) & (N1 - 1);
    cpx Zk = s_c[SW(kk)];
    cpx Zm = s_c[SW(mm)];
    float Ex = 0.5f*(Zk.x + Zm.x), Ey = 0.5f*(Zk.y - Zm.y);
    float Ox = 0.5f*(Zk.y + Zm.y), Oy = 0.5f*(Zm.x - Zk.x);
    float tx = w.x*Ox - w.y*Oy, ty = w.x*Oy + w.y*Ox;
    Xk = make_float2(Ex + tx, Ey + ty);
    Xm = make_float2(Ex - tx, Ey - ty);
}

__global__ __launch_bounds__(64, 2)
void cheaptrick_kernel(const float* __restrict__ x,
                       const float* __restrict__ f0in,
                       float* __restrict__ out)
{
    __shared__ cpx   s_c[1024];
    __shared__ float s_P[1026];
    // s_C aliases s_c (lifetime-disjoint; cross-type boundaries are fenced)
    float* s_C = (float*)s_c;

    const int t  = threadIdx.x;          // 0..63 == lane (single wave)
    const int vv = t & 3;
    const int n  = blockIdx.x;
    const int b  = blockIdx.y;

    float f0 = f0in[b * NFRAMES + n];
    const float F_MIN = 72000.0f / 2045.0f;
    if (f0 <= F_MIN) f0 = 500.0f;

    cpx z[16];

    // ---- pack1: frame extraction + window; z[r] = (v0*w0, v1*w1), m=t+64r.
    //      Window pair (w0,w1) parked in LDS s_c (dead until RT1) to keep
    //      peak VGPR pressure low.
    {
        const float* xrow = x + (size_t)b * TLEN;
        const int base_idx = n * FPER - N1;
        float hwl = rintf(36000.0f / f0);
        float sw2 = 0.0f, swn = 0.0f, sfw = 0.0f;
#pragma unroll
        for (int r = 0; r < 16; ++r) {
            int m  = t + 64 * r;
            int i0 = base_idx + 2 * m;
            float v0, v1;
            if (i0 >= 0 && i0 + 1 <= TLEN - 1) {       // aligned pair (i0 even)
                float2 fv = *reinterpret_cast<const float2*>(xrow + i0);
                v0 = fv.x; v1 = fv.y;
            } else {
                v0 = xrow[max(0, min(TLEN - 1, i0))];
                v1 = xrow[max(0, min(TLEN - 1, i0 + 1))];
            }
            float rel0 = (float)(2 * m - N1);
            float rel1 = rel0 + 1.0f;
            float w0 = 0.0f, w1 = 0.0f;
            if (fabsf(rel0) <= hwl) w0 = 0.5f * __cosf(PIF * rel0 / 36000.0f * f0) + 0.5f;
            if (fabsf(rel1) <= hwl) w1 = 0.5f * __cosf(PIF * rel1 / 36000.0f * f0) + 0.5f;
            sw2 += w0 * w0 + w1 * w1;
            swn += w0 + w1;
            sfw += v0 * w0 + v1 * w1;
            z[r] = make_float2(v0 * w0, v1 * w1);
            s_c[SW(m)] = make_float2(w0, w1);          // park window in LDS
        }
#pragma unroll
        for (int off = 32; off > 0; off >>= 1) {
            sw2 += __shfl_down(sw2, off, 64);
            swn += __shfl_down(swn, off, 64);
            sfw += __shfl_down(sfw, off, 64);
        }
        sw2 = __shfl(sw2, 0, 64);
        swn = __shfl(swn, 0, 64);
        sfw = __shfl(sfw, 0, 64);
        float wscale = 1.0f / sqrtf(sw2);
        float dc = sfw / swn;
#pragma unroll
        for (int r = 0; r < 16; ++r) {
            cpx wnr = s_c[SW(t + 64 * r)];             // read window back
            z[r].x = wscale * (z[r].x - dc * wnr.x);   // exact r2 arithmetic
            z[r].y = wscale * (z[r].y - dc * wnr.y);
        }
    }

    // ---- twiddles, computed once, reused by all 3 FFTs ----
    cpx wA[4], wC[4], wB, wD, wU[8];
    {
        float sn, cs;
#pragma unroll
        for (int j = 0; j < 4; ++j) {
            __sincosf(-PIF * (float)(t + 64 * j) * (1.0f / 512.0f), &sn, &cs);
            wA[j] = make_float2(cs, sn);               // W_1024^(t+64j)
        }
        __sincosf(-PIF * (float)t * (1.0f / 128.0f), &sn, &cs);
        wB = make_float2(cs, sn);                      // W_256^t
#pragma unroll
        for (int a = 0; a < 4; ++a) {
            __sincosf(-PIF * (float)(4 * a + vv) * (1.0f / 32.0f), &sn, &cs);
            wC[a] = make_float2(cs, sn);               // W_64^(4a+v)
        }
        __sincosf(-PIF * (float)vv * (1.0f / 8.0f), &sn, &cs);
        wD = make_float2(cs, sn);                      // W_16^v
#pragma unroll
        for (int c = 0; c < 8; ++c) {
            __sincosf(-PIF * (float)(t + 64 * c) * (1.0f / 1024.0f), &sn, &cs);
            wU[c] = make_float2(cs, sn);               // W_2048^(t+64c)
        }
    }
    const cpx wmid = make_float2(0.0f, -1.0f);         // W_2048^512
    const int r6 = (int)(__brev((unsigned)t) >> 26);   // rev6(t)

#pragma unroll 1
    for (int pass = 0; pass < 3; ++pass) {
        if (pass != 0) {
            // pack even extension of s_P (FFT2: logP ; FFT3: lifted cepstrum)
#pragma unroll
            for (int r = 0; r < 8; ++r) {              // m <= 511: direct pair
                int m = t + 64 * r;
                z[r] = make_float2(s_P[2 * m], s_P[2 * m + 1]);
            }
#pragma unroll
            for (int r = 8; r < 16; ++r) {             // m >= 512: mirrored
                int m = t + 64 * r;
                float v0, v1;
                if (m == 512) { v0 = s_P[1024]; v1 = s_P[1023]; }
                else          { v0 = s_P[2048 - 2 * m]; v1 = s_P[2047 - 2 * m]; }
                z[r] = make_float2(v0, v1);
            }
        }

        // ================= 1024-pt FFT, fully wave-local =================
        // stage A (M=1024): butterflies i0 = t+64j, slots {j, j+4, j+8, j+12}
#pragma unroll
        for (int j = 0; j < 4; ++j) bf4(z[j], z[j+4], z[j+8], z[j+12], wA[j]);
        // stage B (M=256): per 256-block, slots {4q..4q+3}, twiddle W_256^t
#pragma unroll
        for (int q = 0; q < 4; ++q) bf4(z[4*q], z[4*q+1], z[4*q+2], z[4*q+3], wB);
        // RT1: write m = t+64r ; read m = 64*(t>>2) + 4u + (t&3)
#pragma unroll
        for (int r = 0; r < 16; ++r) s_c[(t + 64 * r) ^ r] = z[r];
#pragma unroll
        for (int u = 0; u < 16; ++u) {
            int m = 64 * (t >> 2) + 4 * u + vv;
            z[u] = s_c[m ^ (t >> 2)];
        }
        // stage C (M=64): butterflies r=4a+v, slots {a, a+4, a+8, a+12}
#pragma unroll
        for (int a = 0; a < 4; ++a) bf4(z[a], z[a+4], z[a+8], z[a+12], wC[a]);
        // stage D (M=16): slots {4h..4h+3}, twiddle W_16^v
#pragma unroll
        for (int h = 0; h < 4; ++h) bf4(z[4*h], z[4*h+1], z[4*h+2], z[4*h+3], wD);
        // RT2: write back same layout ; read quads m = 4t + 256c + e
#pragma unroll
        for (int u = 0; u < 16; ++u) {
            int m = 64 * (t >> 2) + 4 * u + vv;
            s_c[m ^ (t >> 2)] = z[u];
        }
#pragma unroll
        for (int c = 0; c < 4; ++c)
#pragma unroll
            for (int e = 0; e < 4; ++e) {
                int m = 4 * t + 256 * c + e;
                z[4 * c + e] = s_c[SW(m)];
            }
        // stage E (M=4), then store un-bit-reversed: k = brev10(m)
#pragma unroll
        for (int c = 0; c < 4; ++c) bf4_last(z[4*c], z[4*c+1], z[4*c+2], z[4*c+3]);
#pragma unroll
        for (int c = 0; c < 4; ++c) {
            int rc = ((c & 1) << 1) | (c >> 1);
#pragma unroll
            for (int e = 0; e < 4; ++e) {
                int re = ((e & 1) << 1) | (e >> 1);
                int k = (re << 8) | (r6 << 2) | rc;
                s_c[SW(k)] = z[4 * c + e];
            }
        }
        // =================================================================

        if (pass == 0) {
            // ---- unpack + power spectrum ----
#pragma unroll
            for (int c = 0; c < 8; ++c) {
                int kk = t + 64 * c;
                cpx Xk, Xm;
                unpack_k(s_c, kk, wU[c], Xk, Xm);
                s_P[kk]        = Xk.x * Xk.x + Xk.y * Xk.y;
                s_P[1024 - kk] = Xm.x * Xm.x + Xm.y * Xm.y;
            }
            if (t == 0) {
                cpx Xk, Xm;
                unpack_k(s_c, 512, wmid, Xk, Xm);
                s_P[512] = Xk.x * Xk.x + Xk.y * Xk.y;
            }

            // ---- sub-f0 replacement (kmax <= 51 < 64; read instrs precede
            //      the write instr in wave program order) ----
            float rate = f0 * (2048.0f / 24000.0f);
            int kmax = (int)floorf(rate);
            if (t <= kmax) {
                float m = rate - (float)t;
                int lo = (int)floorf(m);
                lo = max(0, min(K1 - 2, lo));
                float frac = m - (float)lo;
                float repl = s_P[lo] * (1.0f - frac) + s_P[lo + 1] * frac;
                s_P[t] += repl;
            }

            // fence: s_C(float) stores below must not reorder vs s_c(cpx)
            // loads above (TBAA cross-type alias)
            asm volatile("" ::: "memory");

            // ---- reflected cumsum: serial-19 + wave scan -> s_C ----
            float loc[19];
            float run = 0.0f;
            const int basej = t * 19;
#pragma unroll
            for (int c = 0; c < 19; ++c) {
                int j = basej + c;
                float v = 0.0f;
                if (j < MTOT) {
                    int a = abs(j - KPAD);
                    if (a > N1) a = NFFT - a;
                    v = s_P[a] * (24000.0f / 2048.0f);
                }
                run += v;
                loc[c] = run;
            }
            float sv = run;
#pragma unroll
            for (int off = 1; off < 64; off <<= 1) {
                float o = __shfl_up(sv, off, 64);
                if (t >= off) sv += o;
            }
            float prefix = sv - run;
#pragma unroll
            for (int c = 0; c < 19; ++c) {
                int j = basej + c;
                if (j < MTOT) s_C[j] = prefix + loc[c];
            }

            // ---- rectangular smoothing + log -> s_P ----
            float width = f0 * (2.0f / 3.0f);
            float wbins = width * (2048.0f / 24000.0f);
#pragma unroll
            for (int c = 0; c < 17; ++c) {
                int k = t + 64 * c;
                if (k < K1) {                          // c==16 only t==0
                    float pos_lo = (float)k - 0.5f * wbins + ((float)KPAD - 0.5f);
                    float pos_hi = pos_lo + wbins;
                    int llo = (int)floorf(pos_lo); llo = max(0, min(MTOT - 2, llo));
                    float flo = pos_lo - (float)llo;
                    float clo = s_C[llo] + (s_C[llo + 1] - s_C[llo]) * flo;
                    int lhi = (int)floorf(pos_hi); lhi = max(0, min(MTOT - 2, lhi));
                    float fhi = pos_hi - (float)lhi;
                    float chi = s_C[lhi] + (s_C[lhi + 1] - s_C[lhi]) * fhi;
                    s_P[k] = __logf((chi - clo) / width);
                }
            }

            // fence: next pass's s_c(cpx) stores must not reorder vs the
            // s_C(float) loads above
            asm volatile("" ::: "memory");
        } else if (pass == 1) {
            // ---- unpack + lifter -> s_P ----
#pragma unroll
            for (int c = 0; c < 8; ++c) {
                int kk = t + 64 * c;
                cpx Xk, Xm;
                unpack_k(s_c, kk, wU[c], Xk, Xm);
                {
                    float cep = Xk.x * (1.0f / 2048.0f);
                    float pz = PIF * f0 * ((float)kk * (1.0f / 24000.0f));
                    float s = __sinf(pz);
                    float sl = (kk != 0) ? (s / pz) : 1.0f;
                    s_P[kk] = cep * sl * (1.0f + 0.6f * s * s);
                }
                {
                    int km = 1024 - kk;                // in [513,1024], never 0
                    float cep = Xm.x * (1.0f / 2048.0f);
                    float pz = PIF * f0 * ((float)km * (1.0f / 24000.0f));
                    float s = __sinf(pz);
                    s_P[km] = cep * (s / pz) * (1.0f + 0.6f * s * s);
                }
            }
            if (t == 0) {
                cpx Xk, Xm;
                unpack_k(s_c, 512, wmid, Xk, Xm);
                float cep = Xk.x * (1.0f / 2048.0f);
                float pz = PIF * f0 * (512.0f / 24000.0f);
                float s = __sinf(pz);
                s_P[512] = cep * (s / pz) * (1.0f + 0.6f * s * s);
            }
        } else {
            // ---- unpack + store ----
            float* orow = out + (size_t)(b * NFRAMES + n) * K1;
#pragma unroll
            for (int c = 0; c < 8; ++c) {
                int kk = t + 64 * c;
                cpx Xk, Xm;
                unpack_k(s_c, kk, wU[c], Xk, Xm);
                orow[kk]        = Xk.x;
                orow[1024 - kk] = Xm.x;
            }
            if (t == 0) {
                cpx Xk, Xm;
                unpack_k(s_c, 512, wmid, Xk, Xm);
                orow[512] = Xk.x;
            }
        }
    }
}

extern "C" void kernel_launch(void* const* d_in, const int* in_sizes, int n_in,
                              void* d_out, int out_size, void* d_ws, size_t ws_size,
                              hipStream_t stream) {
    (void)in_sizes; (void)n_in; (void)d_ws; (void)ws_size; (void)out_size;
    const float* x  = (const float*)d_in[0];
    const float* f0 = (const float*)d_in[1];
    float* out = (float*)d_out;
    dim3 grid(NFRAMES, BATCH);
    hipLaunchKernelGGL(cheaptrick_kernel, grid, dim3(64), 0, stream, x, f0, out);
}

// Round 4
// 142.268 us; speedup vs baseline: 3.2122x; 1.6724x over previous
//
#include <hip/hip_runtime.h>
#include <math.h>

#define NFFT   2048
#define N1     1024
#define K1     1025
#define KPAD   36
#define MTOT   1097   // K1 + 2*KPAD
#define NFRAMES 1001
#define TLEN   120000
#define BATCH  8
#define FPER   120
#define PIF 3.14159265358979323846f

// ============================================================================
// One WAVE (64 threads) per frame; 16 cpx/thread; ZERO __syncthreads.
// Math identical to r2/r3 (both passed on HW, absmax 0.03125).
// r2/r3 failed on VGPR spills. Empirical law from those rounds:
//   __launch_bounds__(64, w)  =>  effective VGPR cap = 512/(2*w)
//   (r2 w=4 -> 64 regs; r3 w=2 -> 128 regs; both spilled massively).
// r4 register economy:
//   - __launch_bounds__(64, 1): cap 256 by the observed law.
//   - NO persistent twiddle arrays (was 37 live regs across the whole
//     kernel): every twiddle recomputed by __sincosf at point of use.
//   - Straight-line 3 passes (no rolled pass-loop with mutually exclusive
//     branch bodies): allocator sees each phase's pressure in isolation.
//   Peak live set now ~58 regs (FFT phase).
// Spill canary: FETCH must return to ~15 MB, WRITE to ~32.3 MB. If it fires
// again, abandon wave-per-frame and revert to the r1 4-wave structure.
//
// LDS element swizzle SW(m) = m ^ ((m>>6)&15): enumerated conflict-minimal
// (4 lanes/bank-pair = b64 floor) for all access patterns (see r2 notes).
// ============================================================================

typedef float2 cpx;
__device__ __forceinline__ cpx cadd(cpx a, cpx b){ return make_float2(a.x+b.x, a.y+b.y); }
__device__ __forceinline__ cpx csub(cpx a, cpx b){ return make_float2(a.x-b.x, a.y-b.y); }
__device__ __forceinline__ cpx cmul(cpx a, cpx b){ return make_float2(a.x*b.x - a.y*b.y, a.x*b.y + a.y*b.x); }

__device__ __forceinline__ int SW(int m){ return m ^ ((m >> 6) & 15); }

// W_{den}^idx = exp(-i*pi*idx/(den/2)); inv2den = 1/(den/2)
__device__ __forceinline__ cpx twd(float idx, float inv_half_den){
    float sn, cs;
    __sincosf(-PIF * idx * inv_half_den, &sn, &cs);
    return make_float2(cs, sn);
}

// radix-4 DIF butterfly (two fused radix-2 DIF stages; quarter-order
// q0,q2,q1,q3 -> global bit-reversed output). Arithmetic identical to r1-r3.
__device__ __forceinline__ void bf4(cpx& x0, cpx& x1, cpx& x2, cpx& x3, cpx w1)
{
    cpx w1n = make_float2(w1.y, -w1.x);                       // -i*w1
    cpx w2  = make_float2(w1.x*w1.x - w1.y*w1.y, 2.0f*w1.x*w1.y);
    cpx a1 = cadd(x0, x2);
    cpx c1 = cmul(csub(x0, x2), w1);
    cpx b1 = cadd(x1, x3);
    cpx d1 = cmul(csub(x1, x3), w1n);
    x0 = cadd(a1, b1);
    x1 = cmul(csub(a1, b1), w2);
    x2 = cadd(c1, d1);
    x3 = cmul(csub(c1, d1), w2);
}
// last stage (spans 2/1): twiddles 1 and -i, no multiplies
__device__ __forceinline__ void bf4_last(cpx& x0, cpx& x1, cpx& x2, cpx& x3)
{
    cpx a1 = cadd(x0, x2);
    cpx c1 = csub(x0, x2);
    cpx b1 = cadd(x1, x3);
    cpx bd = csub(x1, x3);
    cpx d1 = make_float2(bd.y, -bd.x);
    x0 = cadd(a1, b1);
    x1 = csub(a1, b1);
    x2 = cadd(c1, d1);
    x3 = csub(c1, d1);
}

// Full 1024-pt FFT from z[16] (natural order m=t+64r) to s_c in NATURAL k
// order. All twiddles computed inside (nothing persists outside).
__device__ __forceinline__ void fft1024(cpx z[16], cpx* s_c, int t)
{
    const int vv = t & 3;
    // stage A (M=1024): slots {j, j+4, j+8, j+12}, w = W_1024^(t+64j)
#pragma unroll
    for (int j = 0; j < 4; ++j)
        bf4(z[j], z[j+4], z[j+8], z[j+12], twd((float)(t + 64*j), 1.0f/512.0f));
    // stage B (M=256): quads, w = W_256^t
    {
        cpx wB = twd((float)t, 1.0f/128.0f);
#pragma unroll
        for (int q = 0; q < 4; ++q) bf4(z[4*q], z[4*q+1], z[4*q+2], z[4*q+3], wB);
    }
    // RT1: write m = t+64r ; read m = 64*(t>>2) + 4u + (t&3)
#pragma unroll
    for (int r = 0; r < 16; ++r) s_c[(t + 64 * r) ^ r] = z[r];
#pragma unroll
    for (int u = 0; u < 16; ++u) {
        int m = 64 * (t >> 2) + 4 * u + vv;
        z[u] = s_c[m ^ (t >> 2)];
    }
    // stage C (M=64): slots {a, a+4, a+8, a+12}, w = W_64^(4a+v)
#pragma unroll
    for (int a = 0; a < 4; ++a)
        bf4(z[a], z[a+4], z[a+8], z[a+12], twd((float)(4*a + vv), 1.0f/32.0f));
    // stage D (M=16): quads, w = W_16^v
    {
        cpx wD = twd((float)vv, 1.0f/8.0f);
#pragma unroll
        for (int h = 0; h < 4; ++h) bf4(z[4*h], z[4*h+1], z[4*h+2], z[4*h+3], wD);
    }
    // RT2: write back same layout ; read quads m = 4t + 256c + e
#pragma unroll
    for (int u = 0; u < 16; ++u) {
        int m = 64 * (t >> 2) + 4 * u + vv;
        s_c[m ^ (t >> 2)] = z[u];
    }
#pragma unroll
    for (int c = 0; c < 4; ++c)
#pragma unroll
        for (int e = 0; e < 4; ++e)
            z[4 * c + e] = s_c[SW(4 * t + 256 * c + e)];
    // stage E (M=4), then store un-bit-reversed: k = brev10(m)
#pragma unroll
    for (int c = 0; c < 4; ++c) bf4_last(z[4*c], z[4*c+1], z[4*c+2], z[4*c+3]);
    const int r6 = (int)(__brev((unsigned)t) >> 26);   // rev6(t)
#pragma unroll
    for (int c = 0; c < 4; ++c) {
        int rc = ((c & 1) << 1) | (c >> 1);
#pragma unroll
        for (int e = 0; e < 4; ++e) {
            int re = ((e & 1) << 1) | (e >> 1);
            int k = (re << 8) | (r6 << 2) | rc;
            s_c[SW(k)] = z[4 * c + e];
        }
    }
}

// pack even extension of s_P (length-2048 real-even -> 1024 cpx, m=t+64r)
__device__ __forceinline__ void pack_even(const float* s_P, cpx z[16], int t)
{
#pragma unroll
    for (int r = 0; r < 8; ++r) {              // m <= 511: direct pair
        int m = t + 64 * r;
        z[r] = make_float2(s_P[2 * m], s_P[2 * m + 1]);
    }
#pragma unroll
    for (int r = 8; r < 16; ++r) {             // m >= 512: mirrored
        int m = t + 64 * r;
        float v0, v1;
        if (m == 512) { v0 = s_P[1024]; v1 = s_P[1023]; }
        else          { v0 = s_P[2048 - 2 * m]; v1 = s_P[2047 - 2 * m]; }
        z[r] = make_float2(v0, v1);
    }
}

// s_c holds Z[k] in NATURAL k order
__device__ __forceinline__ void unpack_k(const cpx* s_c, int kk, cpx w,
                                         cpx& Xk, cpx& Xm)
{
    int mm = (N1 - kk) & (N1 - 1);
    cpx Zk = s_c[SW(kk)];
    cpx Zm = s_c[SW(mm)];
    float Ex = 0.5f*(Zk.x + Zm.x), Ey = 0.5f*(Zk.y - Zm.y);
    float Ox = 0.5f*(Zk.y + Zm.y), Oy = 0.5f*(Zm.x - Zk.x);
    float tx = w.x*Ox - w.y*Oy, ty = w.x*Oy + w.y*Ox;
    Xk = make_float2(Ex + tx, Ey + ty);
    Xm = make_float2(Ex - tx, Ey - ty);
}

__global__ __launch_bounds__(64, 1)
void cheaptrick_kernel(const float* __restrict__ x,
                       const float* __restrict__ f0in,
                       float* __restrict__ out)
{
    __shared__ cpx   s_c[1024];
    __shared__ float s_P[1026];
    // s_C aliases s_c (lifetime-disjoint; cross-type boundaries are fenced)
    float* s_C = (float*)s_c;

    const int t = threadIdx.x;           // 0..63 == lane (single wave)
    const int n = blockIdx.x;
    const int b = blockIdx.y;

    float f0 = f0in[b * NFRAMES + n];
    const float F_MIN = 72000.0f / 2045.0f;
    if (f0 <= F_MIN) f0 = 500.0f;

    cpx z[16];

    // ======================= pass 0: |FFT(win*frame)|^2 =======================
    // pack1: z[r] = (v0*w0, v1*w1), m=t+64r; window pair parked in LDS s_c
    // (dead until RT1) to keep peak VGPR pressure low.
    {
        const float* xrow = x + (size_t)b * TLEN;
        const int base_idx = n * FPER - N1;
        float hwl = rintf(36000.0f / f0);
        float sw2 = 0.0f, swn = 0.0f, sfw = 0.0f;
#pragma unroll
        for (int r = 0; r < 16; ++r) {
            int m  = t + 64 * r;
            int i0 = base_idx + 2 * m;
            float v0, v1;
            if (i0 >= 0 && i0 + 1 <= TLEN - 1) {       // aligned pair (i0 even)
                float2 fv = *reinterpret_cast<const float2*>(xrow + i0);
                v0 = fv.x; v1 = fv.y;
            } else {
                v0 = xrow[max(0, min(TLEN - 1, i0))];
                v1 = xrow[max(0, min(TLEN - 1, i0 + 1))];
            }
            float rel0 = (float)(2 * m - N1);
            float rel1 = rel0 + 1.0f;
            float w0 = 0.0f, w1 = 0.0f;
            if (fabsf(rel0) <= hwl) w0 = 0.5f * __cosf(PIF * rel0 / 36000.0f * f0) + 0.5f;
            if (fabsf(rel1) <= hwl) w1 = 0.5f * __cosf(PIF * rel1 / 36000.0f * f0) + 0.5f;
            sw2 += w0 * w0 + w1 * w1;
            swn += w0 + w1;
            sfw += v0 * w0 + v1 * w1;
            z[r] = make_float2(v0 * w0, v1 * w1);
            s_c[SW(m)] = make_float2(w0, w1);          // park window in LDS
        }
#pragma unroll
        for (int off = 32; off > 0; off >>= 1) {
            sw2 += __shfl_down(sw2, off, 64);
            swn += __shfl_down(swn, off, 64);
            sfw += __shfl_down(sfw, off, 64);
        }
        sw2 = __shfl(sw2, 0, 64);
        swn = __shfl(swn, 0, 64);
        sfw = __shfl(sfw, 0, 64);
        float wscale = 1.0f / sqrtf(sw2);
        float dc = sfw / swn;
#pragma unroll
        for (int r = 0; r < 16; ++r) {
            cpx wnr = s_c[SW(t + 64 * r)];             // read window back
            z[r].x = wscale * (z[r].x - dc * wnr.x);   // exact r2/r3 arithmetic
            z[r].y = wscale * (z[r].y - dc * wnr.y);
        }
    }

    fft1024(z, s_c, t);

    // unpack + power spectrum (w = W_2048^kk, recomputed per use)
#pragma unroll
    for (int c = 0; c < 8; ++c) {
        int kk = t + 64 * c;
        cpx Xk, Xm;
        unpack_k(s_c, kk, twd((float)kk, 1.0f/1024.0f), Xk, Xm);
        s_P[kk]        = Xk.x * Xk.x + Xk.y * Xk.y;
        s_P[1024 - kk] = Xm.x * Xm.x + Xm.y * Xm.y;
    }
    if (t == 0) {
        cpx Xk, Xm;
        unpack_k(s_c, 512, make_float2(0.0f, -1.0f), Xk, Xm);
        s_P[512] = Xk.x * Xk.x + Xk.y * Xk.y;
    }

    // sub-f0 replacement (kmax <= 51 < 64; reads precede the write in wave
    // program order; per-wave DS pipe is in-order)
    {
        float rate = f0 * (2048.0f / 24000.0f);
        int kmax = (int)floorf(rate);
        if (t <= kmax) {
            float m = rate - (float)t;
            int lo = (int)floorf(m);
            lo = max(0, min(K1 - 2, lo));
            float frac = m - (float)lo;
            float repl = s_P[lo] * (1.0f - frac) + s_P[lo + 1] * frac;
            s_P[t] += repl;
        }
    }

    // fence: s_C(float) stores below must not reorder vs s_c(cpx) loads above
    asm volatile("" ::: "memory");

    // reflected cumsum: serial-19 + wave scan -> s_C
    {
        float loc[19];
        float run = 0.0f;
        const int basej = t * 19;
#pragma unroll
        for (int c = 0; c < 19; ++c) {
            int j = basej + c;
            float v = 0.0f;
            if (j < MTOT) {
                int a = abs(j - KPAD);
                if (a > N1) a = NFFT - a;
                v = s_P[a] * (24000.0f / 2048.0f);
            }
            run += v;
            loc[c] = run;
        }
        float sv = run;
#pragma unroll
        for (int off = 1; off < 64; off <<= 1) {
            float o = __shfl_up(sv, off, 64);
            if (t >= off) sv += o;
        }
        float prefix = sv - run;
#pragma unroll
        for (int c = 0; c < 19; ++c) {
            int j = basej + c;
            if (j < MTOT) s_C[j] = prefix + loc[c];
        }
    }

    // rectangular smoothing + log -> s_P
    {
        float width = f0 * (2.0f / 3.0f);
        float wbins = width * (2048.0f / 24000.0f);
#pragma unroll
        for (int c = 0; c < 17; ++c) {
            int k = t + 64 * c;
            if (k < K1) {                              // c==16 only t==0
                float pos_lo = (float)k - 0.5f * wbins + ((float)KPAD - 0.5f);
                float pos_hi = pos_lo + wbins;
                int llo = (int)floorf(pos_lo); llo = max(0, min(MTOT - 2, llo));
                float flo = pos_lo - (float)llo;
                float clo = s_C[llo] + (s_C[llo + 1] - s_C[llo]) * flo;
                int lhi = (int)floorf(pos_hi); lhi = max(0, min(MTOT - 2, lhi));
                float fhi = pos_hi - (float)lhi;
                float chi = s_C[lhi] + (s_C[lhi + 1] - s_C[lhi]) * fhi;
                s_P[k] = __logf((chi - clo) / width);
            }
        }
    }

    // fence: next FFT's s_c(cpx) stores must not reorder vs s_C(float) loads
    asm volatile("" ::: "memory");

    // ======================= pass 1: cepstrum + lifter =======================
    pack_even(s_P, z, t);
    fft1024(z, s_c, t);

#pragma unroll
    for (int c = 0; c < 8; ++c) {
        int kk = t + 64 * c;
        cpx Xk, Xm;
        unpack_k(s_c, kk, twd((float)kk, 1.0f/1024.0f), Xk, Xm);
        {
            float cep = Xk.x * (1.0f / 2048.0f);
            float pz = PIF * f0 * ((float)kk * (1.0f / 24000.0f));
            float s = __sinf(pz);
            float sl = (kk != 0) ? (s / pz) : 1.0f;
            s_P[kk] = cep * sl * (1.0f + 0.6f * s * s);
        }
        {
            int km = 1024 - kk;                        // in [513,1024], never 0
            float cep = Xm.x * (1.0f / 2048.0f);
            float pz = PIF * f0 * ((float)km * (1.0f / 24000.0f));
            float s = __sinf(pz);
            s_P[km] = cep * (s / pz) * (1.0f + 0.6f * s * s);
        }
    }
    if (t == 0) {
        cpx Xk, Xm;
        unpack_k(s_c, 512, make_float2(0.0f, -1.0f), Xk, Xm);
        float cep = Xk.x * (1.0f / 2048.0f);
        float pz = PIF * f0 * (512.0f / 24000.0f);
        float s = __sinf(pz);
        s_P[512] = cep * (s / pz) * (1.0f + 0.6f * s * s);
    }

    // ======================= pass 2: final hfft + store =======================
    pack_even(s_P, z, t);
    fft1024(z, s_c, t);

    float* orow = out + (size_t)(b * NFRAMES + n) * K1;
#pragma unroll
    for (int c = 0; c < 8; ++c) {
        int kk = t + 64 * c;
        cpx Xk, Xm;
        unpack_k(s_c, kk, twd((float)kk, 1.0f/1024.0f), Xk, Xm);
        orow[kk]        = Xk.x;
        orow[1024 - kk] = Xm.x;
    }
    if (t == 0) {
        cpx Xk, Xm;
        unpack_k(s_c, 512, make_float2(0.0f, -1.0f), Xk, Xm);
        orow[512] = Xk.x;
    }
}

extern "C" void kernel_launch(void* const* d_in, const int* in_sizes, int n_in,
                              void* d_out, int out_size, void* d_ws, size_t ws_size,
                              hipStream_t stream) {
    (void)in_sizes; (void)n_in; (void)d_ws; (void)ws_size; (void)out_size;
    const float* x  = (const float*)d_in[0];
    const float* f0 = (const float*)d_in[1];
    float* out = (float*)d_out;
    dim3 grid(NFRAMES, BATCH);
    hipLaunchKernelGGL(cheaptrick_kernel, grid, dim3(64), 0, stream, x, f0, out);
}